// Round 4
// baseline (620.687 us; speedup 1.0000x reference)
//
#include <hip/hip_runtime.h>
#include <math.h>

#define NB 32
#define NS 8192
#define NC 64
#define NM 16
#define NL 4
#define NM2 32                 // 2*M (cos,sin interleaved)
#define NSBF 32                // forward-DFT superblocks per batch

static __device__ __forceinline__ float gelu_exact(float v) {
    return 0.5f * v * (1.0f + erff(v * 0.7071067811865475f));
}

// Build trig table T[s][2m]=cos(2*pi*m*s/NS), T[s][2m+1]=sin(2*pi*m*s/NS)
__global__ void k_table(float* __restrict__ T) {
    int s = blockIdx.x * blockDim.x + threadIdx.x;
    if (s >= NS) return;
    const float w = 6.283185307179586f / (float)NS;
    float* row = T + (size_t)s * NM2;
    #pragma unroll
    for (int m = 0; m < NM; ++m) {
        int idx = (m * s) & (NS - 1);
        float a = w * (float)idx;
        float sv, cv;
        sincosf(a, &sv, &cv);
        row[2*m]   = cv;
        row[2*m+1] = sv;
    }
}

// Transpose Wl_w [L][o][i] -> Wt [L][i][o]; d1_w [o][i] -> d1t [i][o]
__global__ void k_prep(const float* __restrict__ Ww, const float* __restrict__ d1w,
                       float* __restrict__ Wt, float* __restrict__ d1t) {
    int idx = blockIdx.x * 256 + threadIdx.x;
    if (idx < NL*NC*NC) {
        int l = idx / (NC*NC), r = idx % (NC*NC);
        int i = r / NC, o = r % NC;
        Wt[idx] = Ww[(size_t)l*NC*NC + (size_t)o*NC + i];
    } else if (idx < NL*NC*NC + NC*NC) {
        int r = idx - NL*NC*NC;
        int i = r / NC, o = r % NC;
        d1t[r] = d1w[(size_t)o*NC + i];
    }
}

// h[b,s,c] = input[b,s,0]*enc_w[c] + enc_b[c]
__global__ void __launch_bounds__(256) k_enc(const float* __restrict__ x,
                                             const float* __restrict__ ew,
                                             const float* __restrict__ eb,
                                             float* __restrict__ h) {
    int p = blockIdx.x * blockDim.x + threadIdx.x;   // 0..NB*NS-1
    float xv = x[p];
    float4* out = (float4*)(h + (size_t)p * NC);
    #pragma unroll
    for (int q = 0; q < NC/4; ++q) {
        float4 w4 = ((const float4*)ew)[q];
        float4 b4 = ((const float4*)eb)[q];
        out[q] = make_float4(fmaf(xv, w4.x, b4.x), fmaf(xv, w4.y, b4.y),
                             fmaf(xv, w4.z, b4.z), fmaf(xv, w4.w, b4.w));
    }
}

// Forward partial DFT. Wave = 64 channel lanes sharing one position at a time;
// trig row is wave-uniform (s_load). 4 waves/block reduced in LDS.
// partial[b][sb][c][k] = sum_{s in superblock sb} h[b,s,c]*T[s][k]
__global__ void __launch_bounds__(256, 2) k_fwd(const float* __restrict__ h,
                                                const float* __restrict__ T,
                                                float* __restrict__ partial) {
    __shared__ float red[4 * NC * NM2];   // 32 KB
    int b = blockIdx.y, sb = blockIdx.x;
    int t = threadIdx.x;
    int w = t >> 6, lane = t & 63;        // lane = channel c
    const int PPW = NS / NSBF / 4;        // 64 positions per wave
    float acc[NM2];
    #pragma unroll
    for (int k = 0; k < NM2; ++k) acc[k] = 0.f;
    int s0 = sb * (NS / NSBF) + w * PPW;
    const float* hp = h + ((size_t)b*NS + s0)*NC + lane;
    #pragma unroll 2
    for (int it = 0; it < PPW; ++it) {
        float hv = hp[(size_t)it * NC];
        int su = __builtin_amdgcn_readfirstlane(s0 + it);
        const float* trow = T + (size_t)su * NM2;
        #pragma unroll
        for (int k = 0; k < NM2; ++k)
            acc[k] = fmaf(hv, trow[k], acc[k]);
    }
    #pragma unroll
    for (int k = 0; k < NM2; ++k) red[(w*NC + lane)*NM2 + k] = acc[k];
    __syncthreads();
    float* pout = partial + ((size_t)b*NSBF + sb) * (NC*NM2);
    #pragma unroll
    for (int e = 0; e < (NC*NM2)/256; ++e) {
        int idx = t + 256*e;              // idx = c*32 + k
        pout[idx] = red[idx] + red[idx + NC*NM2] + red[idx + 2*NC*NM2]
                  + red[idx + 3*NC*NM2];
    }
}

// Reduce partials -> x_ft, apply complex R mixing, pre-scale for inverse transform.
// Writes TRANSPOSED yst[b][k][o] so k_spec reads o-contiguous (uniform s_loads).
__global__ void __launch_bounds__(256) k_mix(const float* __restrict__ partial,
                                             const float* __restrict__ Rre,
                                             const float* __restrict__ Rim,
                                             float* __restrict__ yst, int l) {
    __shared__ float xf[NC*NM2];   // 8 KB
    int b = blockIdx.x, t = threadIdx.x;
    #pragma unroll
    for (int e = 0; e < (NC*NM2)/256; ++e) {
        int idx = t + 256*e;
        float s = 0.f;
        #pragma unroll 8
        for (int sb = 0; sb < NSBF; ++sb)
            s += partial[((size_t)b*NSBF + sb)*(NC*NM2) + idx];
        xf[idx] = s;
    }
    __syncthreads();
    #pragma unroll
    for (int j = 0; j < (NC*NM)/256; ++j) {    // 4 (o,m) pairs/thread
        int p = t + 256*j;
        int o = p >> 4, m = p & 15;
        float yre = 0.f, yim = 0.f;
        #pragma unroll 8
        for (int i = 0; i < NC; ++i) {
            float xr = xf[i*NM2 + 2*m];
            float xs = xf[i*NM2 + 2*m + 1];
            size_t ridx = (((size_t)l*NC + i)*NC + o)*NM + m;
            float rr = Rre[ridx], ri = Rim[ridx];
            yre = fmaf(xr, rr, yre); yre = fmaf(xs, ri, yre);
            yim = fmaf(xr, ri, yim); yim = fmaf(-xs, rr, yim);
        }
        float* yb = yst + (size_t)b*NM2*NC;
        if (m == 0) { yb[o] = yre * (1.0f/NS); yb[NC + o] = 0.f; }
        else {
            yb[(size_t)(2*m)*NC + o]   = yre * (2.0f/NS);
            yb[(size_t)(2*m+1)*NC + o] = -yim * (2.0f/NS);
        }
    }
}

// Fused spectral + Wl + GELU, in-place on h. One thread = one position.
// acc[64] with ONLY compile-time-constant indices (rule #20: no runtime-indexed
// local arrays); trig chunk lives in a float4 value, never an array.
// Weights/ys read i-outer/o-inner -> wave-uniform s_loads.
__global__ void __launch_bounds__(256, 2) k_spec(float* __restrict__ h,
                                                 const float* __restrict__ T,
                                                 const float* __restrict__ yst,
                                                 const float* __restrict__ Wt,
                                                 const float* __restrict__ Wb,
                                                 int l) {
    int b = blockIdx.y;
    int s = blockIdx.x * 256 + threadIdx.x;
    float* hp = h + ((size_t)b*NS + s)*NC;

    const float* Wl = Wt + (size_t)l*NC*NC;    // [i][o]
    const float* bl = Wb + (size_t)l*NC;
    const float* yb = yst + (size_t)b*NM2*NC;  // [k][o]
    const float4* tg = (const float4*)(T + (size_t)s*NM2);

    float acc[NC];
    #pragma unroll
    for (int o = 0; o < NC; ++o) acc[o] = bl[o];

    // spectral: acc[o] += sum_k T[s][k] * yst[k][o]
    #pragma unroll 1
    for (int k4 = 0; k4 < NM2/4; ++k4) {
        float4 tv = tg[k4];
        const float* y0 = yb + (size_t)(4*k4)*NC;
        #pragma unroll
        for (int o = 0; o < NC; ++o) acc[o] = fmaf(tv.x, y0[o], acc[o]);
        #pragma unroll
        for (int o = 0; o < NC; ++o) acc[o] = fmaf(tv.y, y0[NC + o], acc[o]);
        #pragma unroll
        for (int o = 0; o < NC; ++o) acc[o] = fmaf(tv.z, y0[2*NC + o], acc[o]);
        #pragma unroll
        for (int o = 0; o < NC; ++o) acc[o] = fmaf(tv.w, y0[3*NC + o], acc[o]);
    }

    // dense: acc[o] += sum_i h[i] * Wt[i][o]
    #pragma unroll 1
    for (int i8 = 0; i8 < NC; i8 += 8) {
        float4 v0 = ((const float4*)(hp + i8))[0];
        float4 v1 = ((const float4*)(hp + i8))[1];
        const float* wr = Wl + (size_t)i8*NC;
        #pragma unroll
        for (int o = 0; o < NC; ++o) acc[o] = fmaf(v0.x, wr[o], acc[o]);
        #pragma unroll
        for (int o = 0; o < NC; ++o) acc[o] = fmaf(v0.y, wr[NC + o], acc[o]);
        #pragma unroll
        for (int o = 0; o < NC; ++o) acc[o] = fmaf(v0.z, wr[2*NC + o], acc[o]);
        #pragma unroll
        for (int o = 0; o < NC; ++o) acc[o] = fmaf(v0.w, wr[3*NC + o], acc[o]);
        #pragma unroll
        for (int o = 0; o < NC; ++o) acc[o] = fmaf(v1.x, wr[4*NC + o], acc[o]);
        #pragma unroll
        for (int o = 0; o < NC; ++o) acc[o] = fmaf(v1.y, wr[5*NC + o], acc[o]);
        #pragma unroll
        for (int o = 0; o < NC; ++o) acc[o] = fmaf(v1.z, wr[6*NC + o], acc[o]);
        #pragma unroll
        for (int o = 0; o < NC; ++o) acc[o] = fmaf(v1.w, wr[7*NC + o], acc[o]);
    }

    #pragma unroll
    for (int o4 = 0; o4 < NC/4; ++o4) {
        float4 r;
        r.x = gelu_exact(acc[o4*4+0]);
        r.y = gelu_exact(acc[o4*4+1]);
        r.z = gelu_exact(acc[o4*4+2]);
        r.w = gelu_exact(acc[o4*4+3]);
        ((float4*)hp)[o4] = r;
    }
}

// Fused decoder: out[p] = d2_b + sum_o d2_w[o]*gelu(d1_b[o] + sum_i d1t[i][o]*h[p,i])
__global__ void __launch_bounds__(256, 2) k_dec(const float* __restrict__ h,
                                                const float* __restrict__ d1t,
                                                const float* __restrict__ d1b,
                                                const float* __restrict__ d2w,
                                                const float* __restrict__ d2b,
                                                float* __restrict__ out) {
    int p = blockIdx.x * 256 + threadIdx.x;
    const float* hp = h + (size_t)p * NC;
    float acc[NC];
    #pragma unroll
    for (int o = 0; o < NC; ++o) acc[o] = d1b[o];
    #pragma unroll 1
    for (int i8 = 0; i8 < NC; i8 += 8) {
        float4 v0 = ((const float4*)(hp + i8))[0];
        float4 v1 = ((const float4*)(hp + i8))[1];
        const float* wr = d1t + (size_t)i8*NC;
        #pragma unroll
        for (int o = 0; o < NC; ++o) acc[o] = fmaf(v0.x, wr[o], acc[o]);
        #pragma unroll
        for (int o = 0; o < NC; ++o) acc[o] = fmaf(v0.y, wr[NC + o], acc[o]);
        #pragma unroll
        for (int o = 0; o < NC; ++o) acc[o] = fmaf(v0.z, wr[2*NC + o], acc[o]);
        #pragma unroll
        for (int o = 0; o < NC; ++o) acc[o] = fmaf(v0.w, wr[3*NC + o], acc[o]);
        #pragma unroll
        for (int o = 0; o < NC; ++o) acc[o] = fmaf(v1.x, wr[4*NC + o], acc[o]);
        #pragma unroll
        for (int o = 0; o < NC; ++o) acc[o] = fmaf(v1.y, wr[5*NC + o], acc[o]);
        #pragma unroll
        for (int o = 0; o < NC; ++o) acc[o] = fmaf(v1.z, wr[6*NC + o], acc[o]);
        #pragma unroll
        for (int o = 0; o < NC; ++o) acc[o] = fmaf(v1.w, wr[7*NC + o], acc[o]);
    }
    float res = d2b[0];
    #pragma unroll
    for (int o = 0; o < NC; ++o) res = fmaf(gelu_exact(acc[o]), d2w[o], res);
    out[p] = res;
}

extern "C" void kernel_launch(void* const* d_in, const int* in_sizes, int n_in,
                              void* d_out, int out_size, void* d_ws, size_t ws_size,
                              hipStream_t stream) {
    const float* input = (const float*)d_in[0];
    const float* enc_w = (const float*)d_in[1];
    const float* enc_b = (const float*)d_in[2];
    const float* R_re  = (const float*)d_in[3];
    const float* R_im  = (const float*)d_in[4];
    const float* Wl_w  = (const float*)d_in[5];
    const float* Wl_b  = (const float*)d_in[6];
    const float* d1_w  = (const float*)d_in[7];
    const float* d1_b  = (const float*)d_in[8];
    const float* d2_w  = (const float*)d_in[9];
    const float* d2_b  = (const float*)d_in[10];
    float* out = (float*)d_out;

    float* ws  = (float*)d_ws;
    float* h   = ws;                               // 16.78M floats
    float* T   = h   + (size_t)NB*NS*NC;           // 262144
    float* par = T   + (size_t)NS*NM2;             // NB*NSBF*NC*NM2 = 2.10M
    float* yst = par + (size_t)NB*NSBF*NC*NM2;     // NB*NM2*NC = 65536
    float* Wt  = yst + (size_t)NB*NM2*NC;          // NL*NC*NC = 16384
    float* d1t = Wt  + (size_t)NL*NC*NC;           // NC*NC = 4096

    hipLaunchKernelGGL(k_table, dim3(NS/256), dim3(256), 0, stream, T);
    hipLaunchKernelGGL(k_prep, dim3((NL*NC*NC + NC*NC + 255)/256), dim3(256), 0,
                       stream, Wl_w, d1_w, Wt, d1t);
    hipLaunchKernelGGL(k_enc, dim3((NB*NS)/256), dim3(256), 0, stream,
                       input, enc_w, enc_b, h);
    for (int l = 0; l < NL; ++l) {
        hipLaunchKernelGGL(k_fwd, dim3(NSBF, NB), dim3(256), 0, stream, h, T, par);
        hipLaunchKernelGGL(k_mix, dim3(NB), dim3(256), 0, stream,
                           par, R_re, R_im, yst, l);
        hipLaunchKernelGGL(k_spec, dim3(NS/256, NB), dim3(256), 0, stream,
                           h, T, yst, Wt, Wl_b, l);
    }
    hipLaunchKernelGGL(k_dec, dim3((NB*NS)/256), dim3(256), 0, stream,
                       h, d1t, d1_b, d2_w, d2_b, out);
}

// Round 5
// 565.624 us; speedup vs baseline: 1.0973x; 1.0973x over previous
//
#include <hip/hip_runtime.h>
#include <math.h>

#define NB 32
#define NS 8192
#define NC 64
#define NM 16
#define NL 4
#define NM2 32                 // 2*M (cos,sin interleaved)
#define NSBF 32                // forward-DFT superblocks per batch

typedef float f16v __attribute__((ext_vector_type(16)));

static __device__ __forceinline__ f16v zero16() {
    f16v v;
    #pragma unroll
    for (int j = 0; j < 16; ++j) v[j] = 0.0f;
    return v;
}

static __device__ __forceinline__ float gelu_exact(float v) {
    return 0.5f * v * (1.0f + erff(v * 0.7071067811865475f));
}

// Build trig table T[s][2m]=cos(2*pi*m*s/NS), T[s][2m+1]=sin(2*pi*m*s/NS)
__global__ void k_table(float* __restrict__ T) {
    int s = blockIdx.x * blockDim.x + threadIdx.x;
    if (s >= NS) return;
    const float w = 6.283185307179586f / (float)NS;
    float* row = T + (size_t)s * NM2;
    #pragma unroll
    for (int m = 0; m < NM; ++m) {
        int idx = (m * s) & (NS - 1);
        float a = w * (float)idx;
        float sv, cv;
        sincosf(a, &sv, &cv);
        row[2*m]   = cv;
        row[2*m+1] = sv;
    }
}

// Transpose Wl_w [L][o][i] -> Wt [L][i][o]; d1_w [o][i] -> d1t [i][o]
__global__ void k_prep(const float* __restrict__ Ww, const float* __restrict__ d1w,
                       float* __restrict__ Wt, float* __restrict__ d1t) {
    int idx = blockIdx.x * 256 + threadIdx.x;
    if (idx < NL*NC*NC) {
        int l = idx / (NC*NC), r = idx % (NC*NC);
        int i = r / NC, o = r % NC;
        Wt[idx] = Ww[(size_t)l*NC*NC + (size_t)o*NC + i];
    } else if (idx < NL*NC*NC + NC*NC) {
        int r = idx - NL*NC*NC;
        int i = r / NC, o = r % NC;
        d1t[r] = d1w[(size_t)o*NC + i];
    }
}

// h[b,s,c] = input[b,s,0]*enc_w[c] + enc_b[c]
__global__ void __launch_bounds__(256) k_enc(const float* __restrict__ x,
                                             const float* __restrict__ ew,
                                             const float* __restrict__ eb,
                                             float* __restrict__ h) {
    int p = blockIdx.x * blockDim.x + threadIdx.x;   // 0..NB*NS-1
    float xv = x[p];
    float4* out = (float4*)(h + (size_t)p * NC);
    #pragma unroll
    for (int q = 0; q < NC/4; ++q) {
        float4 w4 = ((const float4*)ew)[q];
        float4 b4 = ((const float4*)eb)[q];
        out[q] = make_float4(fmaf(xv, w4.x, b4.x), fmaf(xv, w4.y, b4.y),
                             fmaf(xv, w4.z, b4.z), fmaf(xv, w4.w, b4.w));
    }
}

// Forward partial DFT. Wave = 64 channel lanes sharing one position at a time;
// trig row is wave-uniform (s_load). Accumulators are ext_vector values (no
// alloca -> no scratch). LDS reduce buffer padded to 33 floats/row so the
// write phase is conflict-free (row stride 132 B, lane stride 33 banks).
__global__ void __launch_bounds__(256) k_fwd(const float* __restrict__ h,
                                             const float* __restrict__ T,
                                             float* __restrict__ partial) {
    __shared__ float red[4 * NC * 33];    // 33.8 KB
    int b = blockIdx.y, sb = blockIdx.x;
    int t = threadIdx.x;
    int w = t >> 6, lane = t & 63;        // lane = channel c
    const int PPW = NS / NSBF / 4;        // 64 positions per wave
    f16v A0 = zero16(), A1 = zero16();
    int s0 = sb * (NS / NSBF) + w * PPW;
    const float* hp = h + ((size_t)b*NS + s0)*NC + lane;
    #pragma unroll 2
    for (int it = 0; it < PPW; ++it) {
        float hv = hp[(size_t)it * NC];
        int su = __builtin_amdgcn_readfirstlane(s0 + it);
        const f16v* tr = (const f16v*)(T + (size_t)su * NM2);
        A0 += hv * tr[0];
        A1 += hv * tr[1];
    }
    float* rr = &red[(w*NC + lane) * 33];
    #pragma unroll
    for (int j = 0; j < 16; ++j) rr[j] = A0[j];
    #pragma unroll
    for (int j = 0; j < 16; ++j) rr[16 + j] = A1[j];
    __syncthreads();
    float* pout = partial + ((size_t)b*NSBF + sb) * (NC*NM2);
    #pragma unroll
    for (int e = 0; e < (NC*NM2)/256; ++e) {
        int idx = t + 256*e;              // idx = c*32 + k
        int c = idx >> 5, k = idx & 31;
        pout[idx] = red[c*33 + k] + red[(NC + c)*33 + k]
                  + red[(2*NC + c)*33 + k] + red[(3*NC + c)*33 + k];
    }
}

// Reduce partials -> x_ft, apply complex R mixing, pre-scale for inverse transform.
// Writes TRANSPOSED yst[b][k][o] so k_spec reads o-contiguous (uniform s_loads).
__global__ void __launch_bounds__(256) k_mix(const float* __restrict__ partial,
                                             const float* __restrict__ Rre,
                                             const float* __restrict__ Rim,
                                             float* __restrict__ yst, int l) {
    __shared__ float xf[NC*NM2];   // 8 KB
    int b = blockIdx.x, t = threadIdx.x;
    #pragma unroll
    for (int e = 0; e < (NC*NM2)/256; ++e) {
        int idx = t + 256*e;
        float s = 0.f;
        #pragma unroll 8
        for (int sb = 0; sb < NSBF; ++sb)
            s += partial[((size_t)b*NSBF + sb)*(NC*NM2) + idx];
        xf[idx] = s;
    }
    __syncthreads();
    #pragma unroll
    for (int j = 0; j < (NC*NM)/256; ++j) {    // 4 (o,m) pairs/thread
        int p = t + 256*j;
        int o = p >> 4, m = p & 15;
        float yre = 0.f, yim = 0.f;
        #pragma unroll 8
        for (int i = 0; i < NC; ++i) {
            float xr = xf[i*NM2 + 2*m];
            float xs = xf[i*NM2 + 2*m + 1];
            size_t ridx = (((size_t)l*NC + i)*NC + o)*NM + m;
            float rr = Rre[ridx], ri = Rim[ridx];
            yre = fmaf(xr, rr, yre); yre = fmaf(xs, ri, yre);
            yim = fmaf(xr, ri, yim); yim = fmaf(-xs, rr, yim);
        }
        float* yb = yst + (size_t)b*NM2*NC;
        if (m == 0) { yb[o] = yre * (1.0f/NS); yb[NC + o] = 0.f; }
        else {
            yb[(size_t)(2*m)*NC + o]   = yre * (2.0f/NS);
            yb[(size_t)(2*m+1)*NC + o] = -yim * (2.0f/NS);
        }
    }
}

// Fused spectral + Wl + GELU, in-place on h. One thread = one position.
// Accumulators are four named f16v ext_vector values -> guaranteed VGPR
// residency (no alloca). Weight/ys rows read as wave-uniform 64B vectors
// -> s_load_dwordx16.
__global__ void __launch_bounds__(256) k_spec(float* __restrict__ h,
                                              const float* __restrict__ T,
                                              const float* __restrict__ yst,
                                              const float* __restrict__ Wt,
                                              const float* __restrict__ Wb,
                                              int l) {
    int b = blockIdx.y;
    int s = blockIdx.x * 256 + threadIdx.x;
    float* hp = h + ((size_t)b*NS + s)*NC;

    const float* Wl = Wt + (size_t)l*NC*NC;    // [i][o]
    const float* bl = Wb + (size_t)l*NC;
    const float* yb = yst + (size_t)b*NM2*NC;  // [k][o]
    const float4* tg = (const float4*)(T + (size_t)s*NM2);

    f16v a0 = ((const f16v*)bl)[0];
    f16v a1 = ((const f16v*)bl)[1];
    f16v a2 = ((const f16v*)bl)[2];
    f16v a3 = ((const f16v*)bl)[3];

    // spectral: a[o] += sum_k T[s][k] * yst[k][o]
    #pragma unroll 1
    for (int k4 = 0; k4 < NM2/4; ++k4) {
        float4 tv = tg[k4];
        const f16v* y = (const f16v*)(yb + (size_t)(4*k4)*NC);
        a0 += tv.x * y[0];  a1 += tv.x * y[1];  a2 += tv.x * y[2];  a3 += tv.x * y[3];
        a0 += tv.y * y[4];  a1 += tv.y * y[5];  a2 += tv.y * y[6];  a3 += tv.y * y[7];
        a0 += tv.z * y[8];  a1 += tv.z * y[9];  a2 += tv.z * y[10]; a3 += tv.z * y[11];
        a0 += tv.w * y[12]; a1 += tv.w * y[13]; a2 += tv.w * y[14]; a3 += tv.w * y[15];
    }

    // dense: a[o] += sum_i h[i] * Wt[i][o]
    #pragma unroll 1
    for (int i4 = 0; i4 < NC; i4 += 4) {
        float4 v = *(const float4*)(hp + i4);
        const f16v* w = (const f16v*)(Wl + (size_t)i4*NC);
        a0 += v.x * w[0];  a1 += v.x * w[1];  a2 += v.x * w[2];  a3 += v.x * w[3];
        a0 += v.y * w[4];  a1 += v.y * w[5];  a2 += v.y * w[6];  a3 += v.y * w[7];
        a0 += v.z * w[8];  a1 += v.z * w[9];  a2 += v.z * w[10]; a3 += v.z * w[11];
        a0 += v.w * w[12]; a1 += v.w * w[13]; a2 += v.w * w[14]; a3 += v.w * w[15];
    }

    f16v g;
    #pragma unroll
    for (int j = 0; j < 16; ++j) g[j] = gelu_exact(a0[j]);
    ((f16v*)hp)[0] = g;
    #pragma unroll
    for (int j = 0; j < 16; ++j) g[j] = gelu_exact(a1[j]);
    ((f16v*)hp)[1] = g;
    #pragma unroll
    for (int j = 0; j < 16; ++j) g[j] = gelu_exact(a2[j]);
    ((f16v*)hp)[2] = g;
    #pragma unroll
    for (int j = 0; j < 16; ++j) g[j] = gelu_exact(a3[j]);
    ((f16v*)hp)[3] = g;
}

// Fused decoder: out[p] = d2_b + sum_o d2_w[o]*gelu(d1_b[o] + sum_i d1t[i][o]*h[p,i])
__global__ void __launch_bounds__(256) k_dec(const float* __restrict__ h,
                                             const float* __restrict__ d1t,
                                             const float* __restrict__ d1b,
                                             const float* __restrict__ d2w,
                                             const float* __restrict__ d2b,
                                             float* __restrict__ out) {
    int p = blockIdx.x * 256 + threadIdx.x;
    const float* hp = h + (size_t)p * NC;
    f16v a0 = ((const f16v*)d1b)[0];
    f16v a1 = ((const f16v*)d1b)[1];
    f16v a2 = ((const f16v*)d1b)[2];
    f16v a3 = ((const f16v*)d1b)[3];
    #pragma unroll 1
    for (int i4 = 0; i4 < NC; i4 += 4) {
        float4 v = *(const float4*)(hp + i4);
        const f16v* w = (const f16v*)(d1t + (size_t)i4*NC);
        a0 += v.x * w[0];  a1 += v.x * w[1];  a2 += v.x * w[2];  a3 += v.x * w[3];
        a0 += v.y * w[4];  a1 += v.y * w[5];  a2 += v.y * w[6];  a3 += v.y * w[7];
        a0 += v.z * w[8];  a1 += v.z * w[9];  a2 += v.z * w[10]; a3 += v.z * w[11];
        a0 += v.w * w[12]; a1 += v.w * w[13]; a2 += v.w * w[14]; a3 += v.w * w[15];
    }
    float res = d2b[0];
    #pragma unroll
    for (int j = 0; j < 16; ++j) res = fmaf(gelu_exact(a0[j]), d2w[j],      res);
    #pragma unroll
    for (int j = 0; j < 16; ++j) res = fmaf(gelu_exact(a1[j]), d2w[16 + j], res);
    #pragma unroll
    for (int j = 0; j < 16; ++j) res = fmaf(gelu_exact(a2[j]), d2w[32 + j], res);
    #pragma unroll
    for (int j = 0; j < 16; ++j) res = fmaf(gelu_exact(a3[j]), d2w[48 + j], res);
    out[p] = res;
}

extern "C" void kernel_launch(void* const* d_in, const int* in_sizes, int n_in,
                              void* d_out, int out_size, void* d_ws, size_t ws_size,
                              hipStream_t stream) {
    const float* input = (const float*)d_in[0];
    const float* enc_w = (const float*)d_in[1];
    const float* enc_b = (const float*)d_in[2];
    const float* R_re  = (const float*)d_in[3];
    const float* R_im  = (const float*)d_in[4];
    const float* Wl_w  = (const float*)d_in[5];
    const float* Wl_b  = (const float*)d_in[6];
    const float* d1_w  = (const float*)d_in[7];
    const float* d1_b  = (const float*)d_in[8];
    const float* d2_w  = (const float*)d_in[9];
    const float* d2_b  = (const float*)d_in[10];
    float* out = (float*)d_out;

    float* ws  = (float*)d_ws;
    float* h   = ws;                               // 16.78M floats
    float* T   = h   + (size_t)NB*NS*NC;           // 262144
    float* par = T   + (size_t)NS*NM2;             // NB*NSBF*NC*NM2 = 2.10M
    float* yst = par + (size_t)NB*NSBF*NC*NM2;     // NB*NM2*NC = 65536
    float* Wt  = yst + (size_t)NB*NM2*NC;          // NL*NC*NC = 16384
    float* d1t = Wt  + (size_t)NL*NC*NC;           // NC*NC = 4096

    hipLaunchKernelGGL(k_table, dim3(NS/256), dim3(256), 0, stream, T);
    hipLaunchKernelGGL(k_prep, dim3((NL*NC*NC + NC*NC + 255)/256), dim3(256), 0,
                       stream, Wl_w, d1_w, Wt, d1t);
    hipLaunchKernelGGL(k_enc, dim3((NB*NS)/256), dim3(256), 0, stream,
                       input, enc_w, enc_b, h);
    for (int l = 0; l < NL; ++l) {
        hipLaunchKernelGGL(k_fwd, dim3(NSBF, NB), dim3(256), 0, stream, h, T, par);
        hipLaunchKernelGGL(k_mix, dim3(NB), dim3(256), 0, stream,
                           par, R_re, R_im, yst, l);
        hipLaunchKernelGGL(k_spec, dim3(NS/256, NB), dim3(256), 0, stream,
                           h, T, yst, Wt, Wl_b, l);
    }
    hipLaunchKernelGGL(k_dec, dim3((NB*NS)/256), dim3(256), 0, stream,
                       h, d1t, d1_b, d2_w, d2_b, out);
}